// Round 6
// baseline (163.455 us; speedup 1.0000x reference)
//
#include <hip/hip_runtime.h>
#include <hip/hip_bf16.h>

#define BB 8
#define TT 32
#define NN 256
#define DD 256
#define HH 8
#define DH 32

typedef __attribute__((ext_vector_type(8))) short short8v;   // 8 bf16 = 4 VGPR
typedef __attribute__((ext_vector_type(4))) float f32x4;
typedef __attribute__((ext_vector_type(16))) float f32x16;
typedef __attribute__((ext_vector_type(2))) unsigned int u32x2;

static __device__ __forceinline__ unsigned short f2bfu(float f) {
    __hip_bfloat16 h = __float2bfloat16(f);
    unsigned short u;
    __builtin_memcpy(&u, &h, 2);
    return u;
}
static __device__ __forceinline__ unsigned int pkbf(float a, float b) {
    float2 f2; f2.x = a; f2.y = b;
    __hip_bfloat162 h2 = __float22bfloat162_rn(f2);
    unsigned int u;
    __builtin_memcpy(&u, &h2, 4);
    return u;
}

// ---------------------------------------------------------------------------
// K0: pre-fragment W matrices into 16x16x32 MFMA B-frag order (bf16).
//   Wf[mat][ctile(16)][kc(8)][lane(64)][8]
// ---------------------------------------------------------------------------
__global__ __launch_bounds__(256) void wfrag_kernel(const float* __restrict__ Wq,
                                                    const float* __restrict__ Wk,
                                                    const float* __restrict__ Wv,
                                                    short* __restrict__ Wf) {
    int bid = blockIdx.x;          // mat*16 + ctile
    int mat = bid >> 4, ctile = bid & 15;
    const float* W = (mat == 0) ? Wq : (mat == 1) ? Wk : Wv;
    short* out = Wf + (size_t)mat * (16 * 8 * 64 * 8) + (size_t)ctile * (8 * 64 * 8);
    int tid = threadIdx.x;         // = k
    int kc = tid >> 5, kg = (tid >> 3) & 3, j = tid & 7;
#pragma unroll
    for (int i = 0; i < 16; ++i) { // i = local col
        float v = W[(size_t)(ctile * 16 + i) * DD + tid];
        int lane = i | (kg << 4);
        out[((size_t)kc * 64 + lane) * 8 + j] = (short)f2bfu(v);
    }
}

// ---------------------------------------------------------------------------
// K1 (fused): single pass over x computes
//   - TAtt (softmax-weighted sum over T; fp32 stats in registers,
//     partner-thread combine through LDS)
//   - Q = x @ Wq^T  (MFMA; Q-tile repacked via LDS, coalesced row-major store
//     Qg[b][t][n][c] bf16)
//   - K,V = TAtt @ {Wk,Wv}^T (epilogue MFMA, scatter to verified frag layouts)
// Block: 1024 threads (16 waves) owns (b, 8 n-rows); 4 t-chunks of 8.
// Register prefetch of the next x-chunk hides HBM latency under compute.
// ---------------------------------------------------------------------------
__global__ __launch_bounds__(1024, 1) void fused_tqkv_kernel(
        const float* __restrict__ x,
        const short* __restrict__ Wqf,
        const short* __restrict__ Wkf,
        const short* __restrict__ Wvf,
        short* __restrict__ Qg,
        short* __restrict__ Kf,
        short* __restrict__ Vf) {
    __shared__ short Xb[64][264];
    int bid = blockIdx.x;
    int b = bid >> 5;
    int n0 = (bid & 31) * 8;
    int tid = threadIdx.x;
    int w = tid >> 6, l = tid & 63;
    int lg = l >> 4, lr = l & 15;
    const f32x4 zero = {0.f, 0.f, 0.f, 0.f};

    int c = w * 16 + lr;           // this lane's output col (0..255)
    short8v bq[8];
#pragma unroll
    for (int kc = 0; kc < 8; ++kc)
        bq[kc] = *(const short8v*)(Wqf + (((size_t)w * 8 + kc) * 64 + l) * 8);

    // prefetch chunk 0
    float4 pf[4];
#pragma unroll
    for (int i = 0; i < 4; ++i) {
        int f = i * 1024 + tid;
        int rr = f >> 6, c4 = f & 63;
        int t = (rr >> 3), n = n0 + (rr & 7);
        pf[i] = *(const float4*)(x + ((size_t)(b * TT + t) * NN + n) * DD + c4 * 4);
    }
    float se[4] = {0.f, 0.f, 0.f, 0.f}, ws[4] = {0.f, 0.f, 0.f, 0.f};

    for (int tc = 0; tc < 4; ++tc) {
        __syncthreads();           // A: Xb free (prior copy phase done)
        // ---- store prefetched x-chunk to LDS (bf16) + fp32 softmax stats ----
#pragma unroll
        for (int i = 0; i < 4; ++i) {
            int f = i * 1024 + tid;
            int rr = f >> 6, c4 = f & 63;
            float4 xv = pf[i];
            short4 sv;
            sv.x = (short)f2bfu(xv.x);
            sv.y = (short)f2bfu(xv.y);
            sv.z = (short)f2bfu(xv.z);
            sv.w = (short)f2bfu(xv.w);
            *(short4*)&Xb[rr][c4 * 4] = sv;
            float e;
            e = __expf(xv.x); se[0] += e; ws[0] += xv.x * e;
            e = __expf(xv.y); se[1] += e; ws[1] += xv.y * e;
            e = __expf(xv.z); se[2] += e; ws[2] += xv.z * e;
            e = __expf(xv.w); se[3] += e; ws[3] += xv.w * e;
        }
        // ---- issue next chunk's loads (fly during compute + copy) ----
        if (tc < 3) {
#pragma unroll
            for (int i = 0; i < 4; ++i) {
                int f = i * 1024 + tid;
                int rr = f >> 6, c4 = f & 63;
                int t = (tc + 1) * 8 + (rr >> 3), n = n0 + (rr & 7);
                pf[i] = *(const float4*)(x + ((size_t)(b * TT + t) * NN + n) * DD + c4 * 4);
            }
        }
        __syncthreads();           // B: x-tile ready
        // ---- qproj MFMA ----
        f32x4 acc[4];
#pragma unroll
        for (int rt4 = 0; rt4 < 4; ++rt4) {
            acc[rt4] = zero;
#pragma unroll
            for (int kc = 0; kc < 8; ++kc) {
                short8v a = *(const short8v*)&Xb[rt4 * 16 + lr][kc * 32 + lg * 8];
                acc[rt4] = __builtin_amdgcn_mfma_f32_16x16x32_bf16(a, bq[kc], acc[rt4], 0, 0, 0);
            }
        }
        __syncthreads();           // C: all Xb reads done -> reuse as Q-tile
#pragma unroll
        for (int rt4 = 0; rt4 < 4; ++rt4)
#pragma unroll
            for (int r = 0; r < 4; ++r)
                Xb[rt4 * 16 + lg * 4 + r][c] = (short)f2bfu(acc[rt4][r]);
        __syncthreads();           // D: Q-tile ready
        // ---- coalesced Q store: Qg[b][t][n][c] ----
#pragma unroll
        for (int i = 0; i < 2; ++i) {
            int f = i * 1024 + tid;
            int row = f >> 5, cq = f & 31;
            int t = tc * 8 + (row >> 3), n = n0 + (row & 7);
            short8v qv = *(const short8v*)&Xb[row][cq * 8];
            *(short8v*)(Qg + ((size_t)(b * TT + t) * NN + n) * 256 + cq * 8) = qv;
        }
    }

    // ---- TAtt: partner combine (tid <-> tid+512 hold complementary t's) ----
    __syncthreads();               // E
    float* scratch = (float*)&Xb[0][0];
    if (tid >= 512) {
        int part = tid & 511;
#pragma unroll
        for (int j = 0; j < 4; ++j) {
            scratch[part * 8 + j] = se[j];
            scratch[part * 8 + 4 + j] = ws[j];
        }
    }
    __syncthreads();               // F
    float tv[4] = {0.f, 0.f, 0.f, 0.f};
    if (tid < 512) {
#pragma unroll
        for (int j = 0; j < 4; ++j) {
            float s = se[j] + scratch[tid * 8 + j];
            float v = ws[j] + scratch[tid * 8 + 4 + j];
            tv[j] = v / s;
        }
    }
    __syncthreads();               // G: scratch consumed
    {
        int n = (tid >> 6) & 7, c4 = tid & 63;
        if (tid < 512) {
            *(unsigned int*)&Xb[n][c4 * 4] = pkbf(tv[0], tv[1]);
            *(unsigned int*)&Xb[n][c4 * 4 + 2] = pkbf(tv[2], tv[3]);
        } else {
            *(unsigned int*)&Xb[8 + n][c4 * 4] = 0u;
            *(unsigned int*)&Xb[8 + n][c4 * 4 + 2] = 0u;
        }
    }
    __syncthreads();               // H: TAtt rows 0..7 staged, 8..15 zero

    // ---- K, V projections for rows n0..n0+7 ----
    int h = c >> 5, kap = c & 31;
#pragma unroll
    for (int mat = 0; mat < 2; ++mat) {
        const short* Wfm = mat ? Wvf : Wkf;
        short8v bfr[8];
#pragma unroll
        for (int kc = 0; kc < 8; ++kc)
            bfr[kc] = *(const short8v*)(Wfm + (((size_t)w * 8 + kc) * 64 + l) * 8);
        f32x4 acc = zero;
#pragma unroll
        for (int kc = 0; kc < 8; ++kc) {
            short8v a = *(const short8v*)&Xb[lr][kc * 32 + lg * 8];
            acc = __builtin_amdgcn_mfma_f32_16x16x32_bf16(a, bfr[kc], acc, 0, 0, 0);
        }
        if (lg < 2) {   // valid rows 0..7
#pragma unroll
            for (int r = 0; r < 4; ++r) {
                int n = n0 + lg * 4 + r;
                if (mat == 0) {
                    float val = acc[r] * 0.17677669529663688f;  // fold 1/sqrt(32)
                    size_t o = ((((size_t)(b * HH + h) * 8 + (n >> 5)) * 2 + (kap >> 4)) * 64
                                + (n & 31) + 32 * ((kap >> 3) & 1)) * 8 + (kap & 7);
                    Kf[o] = (short)f2bfu(val);
                } else {
                    size_t o = ((((size_t)(b * HH + h) * 8 + (n >> 5)) * 2 + ((n >> 4) & 1)) * 64
                                + kap + 32 * ((n >> 3) & 1)) * 8 + (n & 7);
                    Vf[o] = (short)f2bfu(acc[r]);
                }
            }
        }
    }
}

// ---------------------------------------------------------------------------
// K4: per (b,t,h): swapped QK^T (32x32x16) -> P rows lane-local -> relu + I
// -> cvt_pk + permlane32_swap -> PV (32x32x16). No LDS.
// Q now read from row-major Qg[b][t][n][c] (same fragment semantics).
// ---------------------------------------------------------------------------
__global__ __launch_bounds__(256, 4) void attn_kernel(const short* __restrict__ Qg,
                                                      const short* __restrict__ Kf,
                                                      const short* __restrict__ Vf,
                                                      float* __restrict__ out) {
    int bid = blockIdx.x;          // (b*T + t)*H + h
    int h = bid & 7;
    int t = (bid >> 3) & 31;
    int b = bid >> 8;
    int tid = threadIdx.x;
    int w = tid >> 6, l = tid & 63;
    int pos = l & 31, hi = l >> 5;

    // Q B-frags from row-major: lane(pos,hi), frag(qt,kc) at
    //   (qt*32+pos)*256 + h*32 + kc*16 + hi*8
    const short* qlane = Qg + ((size_t)(b * TT + t) * NN) * 256 + h * 32 + pos * 256 + hi * 8;
    short8v qf00 = *(const short8v*)(qlane + (2 * w + 0) * 8192);
    short8v qf01 = *(const short8v*)(qlane + (2 * w + 0) * 8192 + 16);
    short8v qf10 = *(const short8v*)(qlane + (2 * w + 1) * 8192);
    short8v qf11 = *(const short8v*)(qlane + (2 * w + 1) * 8192 + 16);

    const short8v* kp = (const short8v*)Kf + (size_t)(b * HH + h) * 16 * 64 + l;
    const short8v* vp = (const short8v*)Vf + (size_t)(b * HH + h) * 16 * 64 + l;

    const f32x16 z16 = {};
    f32x16 o0 = z16, o1 = z16;

#pragma unroll 2
    for (int mt = 0; mt < 8; ++mt) {
        short8v kf0 = kp[mt * 128];
        short8v kf1 = kp[mt * 128 + 64];
        short8v vf0 = vp[mt * 128];
        short8v vf1 = vp[mt * 128 + 64];
#pragma unroll
        for (int qi = 0; qi < 2; ++qi) {
            short8v qa = qi ? qf10 : qf00;
            short8v qb = qi ? qf11 : qf01;
            f32x16 p = __builtin_amdgcn_mfma_f32_32x32x16_bf16(kf0, qa, z16, 0, 0, 0);
            p = __builtin_amdgcn_mfma_f32_32x32x16_bf16(kf1, qb, p, 0, 0, 0);
#pragma unroll
            for (int r = 0; r < 16; ++r) p[r] = fmaxf(p[r], 0.f);
            if (mt == 2 * w + qi) {
#pragma unroll
                for (int r = 0; r < 16; ++r) {
                    int mloc = (r & 3) + 8 * (r >> 2) + 4 * hi;
                    if (mloc == pos) p[r] += 1.f;
                }
            }
#pragma unroll
            for (int cc = 0; cc < 2; ++cc) {
                unsigned int A0 = pkbf(p[8 * cc + 0], p[8 * cc + 1]);
                unsigned int A1 = pkbf(p[8 * cc + 2], p[8 * cc + 3]);
                unsigned int B0 = pkbf(p[8 * cc + 4], p[8 * cc + 5]);
                unsigned int B1 = pkbf(p[8 * cc + 6], p[8 * cc + 7]);
                u32x2 s0 = __builtin_amdgcn_permlane32_swap(A0, B0, false, false);
                u32x2 s1 = __builtin_amdgcn_permlane32_swap(A1, B1, false, false);
                union { unsigned int u[4]; short8v s; } pa;
                pa.u[0] = s0[0];
                pa.u[1] = s1[0];
                pa.u[2] = s0[1];
                pa.u[3] = s1[1];
                short8v vv = cc ? vf1 : vf0;
                if (qi == 0)
                    o0 = __builtin_amdgcn_mfma_f32_32x32x16_bf16(pa.s, vv, o0, 0, 0, 0);
                else
                    o1 = __builtin_amdgcn_mfma_f32_32x32x16_bf16(pa.s, vv, o1, 0, 0, 0);
            }
        }
    }

    float* ob = out + ((size_t)(b * TT + t) * NN) * DD + h * DH + pos;
#pragma unroll
    for (int r = 0; r < 16; ++r) {
        int mloc = (r & 3) + 8 * (r >> 2) + 4 * hi;
        ob[(size_t)((2 * w + 0) * 32 + mloc) * DD] = o0[r];
        ob[(size_t)((2 * w + 1) * 32 + mloc) * DD] = o1[r];
    }
}

// ---------------------------------------------------------------------------
extern "C" void kernel_launch(void* const* d_in, const int* in_sizes, int n_in,
                              void* d_out, int out_size, void* d_ws, size_t ws_size,
                              hipStream_t stream) {
    (void)in_sizes; (void)n_in; (void)out_size; (void)ws_size;
    const float* x  = (const float*)d_in[0];
    // d_in[1] = boxes_in_flat: unused by the reference forward.
    const float* Wq = (const float*)d_in[2];
    const float* Wk = (const float*)d_in[3];
    const float* Wv = (const float*)d_in[4];
    float* out = (float*)d_out;

    // ws (bytes): Kf [1MB] | Vf [1MB] | Qg [33.5MB @2MB] | Wf [384KB @36MB]
    char* base = (char*)d_ws;
    short* Kfp = (short*)base;
    short* Vfp = (short*)(base + (size_t)1 * 1024 * 1024);
    short* Qgp = (short*)(base + (size_t)2 * 1024 * 1024);
    short* Wf  = (short*)(base + (size_t)36 * 1024 * 1024);
    short* Wqf = Wf;
    short* Wkf = Wf + (size_t)16 * 8 * 64 * 8;
    short* Wvf = Wkf + (size_t)16 * 8 * 64 * 8;

    wfrag_kernel<<<48, 256, 0, stream>>>(Wq, Wk, Wv, Wf);
    fused_tqkv_kernel<<<BB * 32, 1024, 0, stream>>>(x, Wqf, Wkf, Wvf, Qgp, Kfp, Vfp);
    attn_kernel<<<BB * TT * HH, 256, 0, stream>>>(Qgp, Kfp, Vfp, out);
}